// Round 6
// baseline (1306.300 us; speedup 1.0000x reference)
//
#include <hip/hip_runtime.h>

typedef unsigned short bf16_t;

// ===========================================================================
// Round 6. Established by R1-R5 elimination:
//   - inputs x/W*/b* are FP32 (reading as bf16 manufactured NaN in R1-R3;
//     R5's dtype-adaptive pipeline ran NaN-free => detector chose fp32)
//   - edge_index likely int64 (detector-adaptive either way)
//   - d_out is FP32 (reference output dtype; R5 wrote bf16 -> absmax 0.867
//     ~ element-shuffled readback, the predicted signature of wrong out fmt)
//   - ws_size >= 23 MB (R4 tripwire did not fire); this layout uses 20.5 MB
// Pipeline: CSR build; h0A=x@W1[:,0:64] -> L; hA=leaky(A h0A+b1a) ->bf16 H1;
//   h0B -> L; hB -> M(fp32); haB=A hB -> L; haA=A hA -> M; 
//   [mu|lv] = [haA|haB]@[Wmu;Wlv]+[bmu|blv] -> M,L in-place (row-disjoint).
// M = d_out[0..P) (mu), L = d_out[P..2P) (logvar), P = N*64 fp32.
// ===========================================================================

__device__ __forceinline__ float bf2f(unsigned short u) {
    unsigned int v = ((unsigned int)u) << 16;
    float f;
    __builtin_memcpy(&f, &v, 4);
    return f;
}
__device__ __forceinline__ unsigned short f2bf(float f) {
    unsigned int x;
    __builtin_memcpy(&x, &f, 4);
    unsigned int r = x + 0x7fffu + ((x >> 16) & 1u);
    return (unsigned short)(r >> 16);
}
__device__ __forceinline__ float ldf(const void* p, long long i, unsigned f32) {
    return f32 ? ((const float*)p)[i] : bf2f(((const unsigned short*)p)[i]);
}
__device__ __forceinline__ int ldi(const void* p, long long i, unsigned i64) {
    return i64 ? (int)((const long long*)p)[i] : ((const int*)p)[i];
}

__global__ __launch_bounds__(256) void k_zero(unsigned* __restrict__ p, int n) {
    int i = blockIdx.x * 256 + threadIdx.x;
    if (i < n) p[i] = 0;
}

// ---- format detector: flags[0]=x_f32, flags[1]=W_f32, flags[2]=ei_i64 ------
__global__ __launch_bounds__(256) void k_detect(const void* x, const void* W1,
                                                const void* ei, unsigned* flags) {
    __shared__ float smx[256];
    __shared__ float smw[256];
    __shared__ int   szc[256];
    int tid = threadIdx.x;
    const unsigned short* xu = (const unsigned short*)x;
    float mx = 0.f;
    for (int i = tid; i < 4096; i += 256) {
        unsigned short w = xu[i];
        if ((w & 0x7fffu) >= 0x7f80u) mx = 1e30f;
        else { float f = fabsf(bf2f(w)); if (f > mx) mx = f; }
    }
    smx[tid] = mx;
    const unsigned short* wu = (const unsigned short*)W1;
    float mw = 0.f;
    for (int i = tid; i < 4096; i += 256) {
        unsigned short w = wu[i];
        if ((w & 0x7fffu) >= 0x7f80u) mw = 1e30f;
        else { float f = fabsf(bf2f(w)); if (f > mw) mw = f; }
    }
    smw[tid] = mw;
    const int* eu = (const int*)ei;
    int zc = 0;
    for (int i = tid; i < 128; i += 256)
        if ((i & 1) && eu[i] == 0) ++zc;
    szc[tid] = zc;
    __syncthreads();
    for (int off = 128; off > 0; off >>= 1) {
        if (tid < off) {
            if (smx[tid + off] > smx[tid]) smx[tid] = smx[tid + off];
            if (smw[tid + off] > smw[tid]) smw[tid] = smw[tid + off];
            szc[tid] += szc[tid + off];
        }
        __syncthreads();
    }
    if (tid == 0) {
        flags[0] = (smx[0] > 1e4f) ? 1u : 0u;   // bf16 N(0,1) would max ~4
        flags[1] = (smw[0] > 10.f) ? 1u : 0u;   // glorot |W| <= 0.18
        flags[2] = (szc[0] >= 56) ? 1u : 0u;    // int64 high words all zero
    }
}

// ---- degree count ----------------------------------------------------------
__global__ __launch_bounds__(256) void k_count(const void* ei, const unsigned* det,
                                               int* __restrict__ cnt, int E, int N) {
    int e = blockIdx.x * 256 + threadIdx.x;
    if (e >= E) return;
    int d = ldi(ei, (long long)E + e, det[2]);
    if ((unsigned)d < (unsigned)N) atomicAdd(&cnt[d], 1);
}

__global__ __launch_bounds__(256) void k_dinv(const int* __restrict__ cnt,
                                              float* __restrict__ dinv, int N) {
    int i = blockIdx.x * 256 + threadIdx.x;
    if (i < N) dinv[i] = rsqrtf((float)cnt[i] + 1.0f);  // +1 self-loop
}

// ---- exclusive scan (3-phase) ----------------------------------------------
__global__ __launch_bounds__(256) void k_scan_blk(const int* __restrict__ cnt,
                                                  int* __restrict__ pos,
                                                  int* __restrict__ bsum, int N) {
    __shared__ int sh[256];
    const int tid = threadIdx.x;
    const int base = blockIdx.x * 1024 + tid * 4;
    int v[4];
#pragma unroll
    for (int j = 0; j < 4; ++j) v[j] = (base + j < N) ? cnt[base + j] : 0;
    int s = v[0] + v[1] + v[2] + v[3];
    sh[tid] = s;
    __syncthreads();
    for (int off = 1; off < 256; off <<= 1) {
        int t = (tid >= off) ? sh[tid - off] : 0;
        __syncthreads();
        sh[tid] += t;
        __syncthreads();
    }
    int run = sh[tid] - s;
#pragma unroll
    for (int j = 0; j < 4; ++j) {
        if (base + j < N) pos[base + j] = run;
        run += v[j];
    }
    if (tid == 255) bsum[blockIdx.x] = sh[255];
}

__global__ void k_scan_top(int* __restrict__ bsum, int nb) {
    if (threadIdx.x == 0 && blockIdx.x == 0) {
        int running = 0;
        for (int b = 0; b < nb; ++b) {
            int t = bsum[b];
            bsum[b] = running;
            running += t;
        }
    }
}

__global__ __launch_bounds__(256) void k_scan_add(int* __restrict__ pos,
                                                  const int* __restrict__ bsum, int N) {
    int add = bsum[blockIdx.x];
    int base = blockIdx.x * 1024;
    for (int i = threadIdx.x; i < 1024; i += 256)
        if (base + i < N) pos[base + i] += add;
}

// ---- CSR fill: srt[slot]=src bucketed by dst; pos becomes end --------------
__global__ __launch_bounds__(256) void k_fill(const void* ei, const unsigned* det,
                                              int* __restrict__ pos,
                                              int* __restrict__ srt, int E, int N) {
    int e = blockIdx.x * 256 + threadIdx.x;
    if (e >= E) return;
    unsigned i64 = det[2];
    int s = ldi(ei, e, i64);
    int d = ldi(ei, (long long)E + e, i64);
    if ((unsigned)d < (unsigned)N) {
        int slot = atomicAdd(&pos[d], 1);
        srt[slot] = ((unsigned)s < (unsigned)N) ? s : d;
    }
}

// ---- gemm1: C[N,64](fp32) = x[N,256] @ W1[:, c0:c0+64] ---------------------
__global__ __launch_bounds__(256) void k_gemm1(const void* x, const void* W1,
                                               const unsigned* det, int c0,
                                               float* __restrict__ C) {
    __shared__ float xs[32][33];
    __shared__ float wsh[32][64];
    const unsigned xf = det[0], wf = det[1];
    const int tid = threadIdx.x;
    const int r0 = blockIdx.x * 32;           // N % 32 == 0
    const int col = (tid & 15) * 4;
    const int row = (tid >> 4) * 2;
    float acc[2][4] = {};
    for (int k0 = 0; k0 < 256; k0 += 32) {
        for (int idx = tid; idx < 32 * 32; idx += 256) {
            int r = idx >> 5, kk = idx & 31;
            xs[r][kk] = ldf(x, (long long)(r0 + r) * 256 + k0 + kk, xf);
        }
        for (int idx = tid; idx < 32 * 64; idx += 256) {
            int kk = idx >> 6, c = idx & 63;
            wsh[kk][c] = ldf(W1, (long long)(k0 + kk) * 128 + c0 + c, wf);
        }
        __syncthreads();
#pragma unroll
        for (int kk = 0; kk < 32; ++kk) {
            float a0 = xs[row + 0][kk];
            float a1 = xs[row + 1][kk];
            const float4 b = *(const float4*)&wsh[kk][col];
            acc[0][0] += a0 * b.x; acc[0][1] += a0 * b.y; acc[0][2] += a0 * b.z; acc[0][3] += a0 * b.w;
            acc[1][0] += a1 * b.x; acc[1][1] += a1 * b.y; acc[1][2] += a1 * b.z; acc[1][3] += a1 * b.w;
        }
        __syncthreads();
    }
#pragma unroll
    for (int i = 0; i < 2; ++i)
#pragma unroll
        for (int j = 0; j < 4; ++j)
            C[(long long)(r0 + row + i) * 64 + col + j] = acc[i][j];
}

// ---- gather over 64-col panel: out = Ahat*hsrc (+bias,+leaky) --------------
// formats are launch-time choices for internal buffers; bias uses det[1]
__global__ __launch_bounds__(256) void k_gather(const void* hsrc, int inF32,
                                                const int* __restrict__ srt,
                                                const int* __restrict__ cnt,
                                                const int* __restrict__ pos,
                                                const float* __restrict__ dinv,
                                                const void* bias, const unsigned* det,
                                                int biasOff, int leaky,
                                                void* out, int outF32, int N) {
    int node = blockIdx.x * 4 + (threadIdx.x >> 6);
    if (node >= N) return;
    int lane = threadIdx.x & 63;
    int end = pos[node];
    int beg = end - cnt[node];
    float dd = dinv[node];
    float a = ldf(hsrc, (long long)node * 64 + lane, inF32) * dd * dd;  // self
    for (int q = beg; q < end; ++q) {
        int s = srt[q];
        a += ldf(hsrc, (long long)s * 64 + lane, inF32) * dinv[s] * dd;
    }
    if (bias) a += ldf(bias, biasOff + lane, det[1]);
    if (leaky) a = (a >= 0.f) ? a : 0.01f * a;
    if (outF32) ((float*)out)[(long long)node * 64 + lane] = a;
    else ((bf16_t*)out)[(long long)node * 64 + lane] = f2bf(a);
}

// ---- gemm2: [mu|lv] = [haA|haB] @ [Wmu;Wlv] + [bmu|blv] --------------------
// outMu aliases haA, outLv aliases haB (in-place): each block reads only its
// own 32 rows (staged to LDS inside the k-loop, all reads complete before the
// post-loop epilogue) and writes only its own rows; blocks are row-disjoint.
// NOTE: no __restrict__ on aliased pointers.
__global__ __launch_bounds__(256) void k_gemm2(const float* haA, const float* haB,
                                               const void* Wmu, const void* Wlv,
                                               const void* bmu, const void* blv,
                                               const unsigned* det,
                                               float* outMu, float* outLv) {
    __shared__ float as[32][33];
    __shared__ float wsh[32][128];
    const unsigned wf = det[1];
    const int tid = threadIdx.x;
    const int r0 = blockIdx.x * 32;
    const int col = (tid & 31) * 4;
    const int row = (tid >> 5) * 4;
    float acc[4][4] = {};
    for (int k0 = 0; k0 < 128; k0 += 32) {
        const float* A = (k0 < 64) ? (haA + k0) : (haB + (k0 - 64));
        for (int idx = tid; idx < 32 * 32; idx += 256) {
            int r = idx >> 5, kk = idx & 31;
            as[r][kk] = A[(long long)(r0 + r) * 64 + kk];
        }
        for (int idx = tid; idx < 32 * 128; idx += 256) {
            int kk = idx >> 7, c = idx & 127;
            wsh[kk][c] = (c < 64) ? ldf(Wmu, (long long)(k0 + kk) * 64 + c, wf)
                                  : ldf(Wlv, (long long)(k0 + kk) * 64 + (c - 64), wf);
        }
        __syncthreads();
#pragma unroll
        for (int kk = 0; kk < 32; ++kk) {
            float a0 = as[row + 0][kk];
            float a1 = as[row + 1][kk];
            float a2 = as[row + 2][kk];
            float a3 = as[row + 3][kk];
            const float4 b = *(const float4*)&wsh[kk][col];
            acc[0][0] += a0 * b.x; acc[0][1] += a0 * b.y; acc[0][2] += a0 * b.z; acc[0][3] += a0 * b.w;
            acc[1][0] += a1 * b.x; acc[1][1] += a1 * b.y; acc[1][2] += a1 * b.z; acc[1][3] += a1 * b.w;
            acc[2][0] += a2 * b.x; acc[2][1] += a2 * b.y; acc[2][2] += a2 * b.z; acc[2][3] += a2 * b.w;
            acc[3][0] += a3 * b.x; acc[3][1] += a3 * b.y; acc[3][2] += a3 * b.z; acc[3][3] += a3 * b.w;
        }
        __syncthreads();
    }
#pragma unroll
    for (int i = 0; i < 4; ++i)
#pragma unroll
        for (int j = 0; j < 4; ++j) {
            int c = col + j;
            float v = acc[i][j];
            if (c < 64) {
                v += ldf(bmu, c, wf);
                outMu[(long long)(r0 + row + i) * 64 + c] = v;
            } else {
                v += ldf(blv, c - 64, wf);
                outLv[(long long)(r0 + row + i) * 64 + (c - 64)] = v;
            }
        }
}

__global__ void k_sentinel(float* out, long long lvOff) {
    if (threadIdx.x == 0 && blockIdx.x == 0) {
        out[0] = 9.99e5f;
        out[lvOff] = 9.98e5f;
    }
}

extern "C" void kernel_launch(void* const* d_in, const int* in_sizes, int n_in,
                              void* d_out, int out_size, void* d_ws, size_t ws_size,
                              hipStream_t stream) {
    (void)out_size;
    const int N = 100000, E = 1600000;
    bool ok = (n_in == 8) && in_sizes[0] == 25600000 && in_sizes[1] == 3200000 &&
              in_sizes[2] == 32768 && in_sizes[3] == 128 &&
              in_sizes[4] == 8192 && in_sizes[5] == 64 &&
              in_sizes[6] == 8192 && in_sizes[7] == 64 &&
              ws_size >= (size_t)21 * 1024 * 1024;
    if (!ok) {  // proven non-firing in R4; kept as tripwire
        k_sentinel<<<1, 64, 0, stream>>>((float*)d_out, (long long)N * 64);
        return;
    }
    const void* x   = d_in[0];
    const void* ei  = d_in[1];
    const void* W1  = d_in[2];
    const void* b1  = d_in[3];
    const void* Wmu = d_in[4];
    const void* bmu = d_in[5];
    const void* Wlv = d_in[6];
    const void* blv = d_in[7];

    char* w = (char*)d_ws;
    auto carve = [&](size_t bytes) {
        char* p = w;
        w += (bytes + 255) & ~(size_t)255;
        return p;
    };
    unsigned* flags = (unsigned*)carve(64);
    int*    cnt  = (int*)carve((size_t)N * 4);
    int*    pos  = (int*)carve((size_t)N * 4);
    float*  dinv = (float*)carve((size_t)N * 4);
    int*    bsum = (int*)carve(4096);
    int*    srt  = (int*)carve((size_t)E * 4);           // 6.4 MB
    bf16_t* H1   = (bf16_t*)carve((size_t)N * 64 * 2);   // 12.8 MB; total 20.5 MB

    float* M = (float*)d_out;                 // mu region, also fp32 panel
    float* L = M + (size_t)N * 64;            // logvar region, also fp32 panel

    const int nb = (N + 1023) / 1024;
    const int gblk = (N + 3) / 4;

    k_zero<<<1, 64, 0, stream>>>(flags, 16);
    k_detect<<<1, 256, 0, stream>>>(x, W1, ei, flags);
    k_zero<<<(N + 255) / 256, 256, 0, stream>>>((unsigned*)cnt, N);

    k_count<<<(E + 255) / 256, 256, 0, stream>>>(ei, flags, cnt, E, N);
    k_dinv<<<(N + 255) / 256, 256, 0, stream>>>(cnt, dinv, N);
    k_scan_blk<<<nb, 256, 0, stream>>>(cnt, pos, bsum, N);
    k_scan_top<<<1, 64, 0, stream>>>(bsum, nb);
    k_scan_add<<<nb, 256, 0, stream>>>(pos, bsum, N);
    k_fill<<<(E + 255) / 256, 256, 0, stream>>>(ei, flags, pos, srt, E, N);

    // layer 1, cols 0..63:  h0A -> L ; hA = leaky(A h0A + b1[0:64]) -> H1 (bf16)
    k_gemm1<<<N / 32, 256, 0, stream>>>(x, W1, flags, 0, L);
    k_gather<<<gblk, 256, 0, stream>>>(L, 1, srt, cnt, pos, dinv, b1, flags, 0, 1,
                                       H1, 0, N);
    // layer 1, cols 64..127: h0B -> L ; hB -> M (fp32)
    k_gemm1<<<N / 32, 256, 0, stream>>>(x, W1, flags, 64, L);
    k_gather<<<gblk, 256, 0, stream>>>(L, 1, srt, cnt, pos, dinv, b1, flags, 64, 1,
                                       M, 1, N);
    // layer 2 aggregation first (A(hW) = (Ah)W):
    k_gather<<<gblk, 256, 0, stream>>>(M, 1, srt, cnt, pos, dinv, nullptr, flags,
                                       0, 0, L, 1, N);   // haB -> L
    k_gather<<<gblk, 256, 0, stream>>>(H1, 0, srt, cnt, pos, dinv, nullptr, flags,
                                       0, 0, M, 1, N);   // haA -> M
    // final: [mu|lv] = [haA|haB] @ [Wmu;Wlv] + bias, in-place over M/L
    k_gemm2<<<N / 32, 256, 0, stream>>>(M, L, Wmu, Wlv, bmu, blv, flags, M, L);
}

// Round 7
// 791.379 us; speedup vs baseline: 1.6507x; 1.6507x over previous
//
#include <hip/hip_runtime.h>

typedef unsigned short bf16_t;

// ===========================================================================
// Round 7 (R6 passed @1306us). Facts: inputs fp32, edge_index int64 (detector
// keeps it adaptive), d_out fp32 mu||lv, ws >= 23 MiB (we use ~7.6 MB).
// R6 profile: 4x k_gather = 784us, latency-bound (HBM 7.6%, VALU 16%).
// Changes:
//  - 128-col bf16 feature panels (same 256 B/row as 64-col fp32): 4->2 passes
//  - producer-side pre-scale by dinv (msg = dd * sum h'[s]; no per-edge dinv)
//  - 8-way predicated unroll: 8 independent row loads in flight per wave
//  - single merged gemm1 (one pass over x, 102 MB not 204)
// Buffers: M=d_out[0:P) fp32 mu region, L=d_out[P:2P). Panels (bf16[N,128],
// 25.6MB) live in M/L: h0'->M, h'->L, ha->M, gemm2 in-place M/L (row-disjoint).
// ===========================================================================

__device__ __forceinline__ float bf2f(unsigned short u) {
    unsigned int v = ((unsigned int)u) << 16;
    float f;
    __builtin_memcpy(&f, &v, 4);
    return f;
}
__device__ __forceinline__ unsigned short f2bf(float f) {
    unsigned int x;
    __builtin_memcpy(&x, &f, 4);
    unsigned int r = x + 0x7fffu + ((x >> 16) & 1u);
    return (unsigned short)(r >> 16);
}
__device__ __forceinline__ unsigned pack2(float a, float b) {
    return (unsigned)f2bf(a) | ((unsigned)f2bf(b) << 16);
}
__device__ __forceinline__ float ldf(const void* p, long long i, unsigned f32) {
    return f32 ? ((const float*)p)[i] : bf2f(((const unsigned short*)p)[i]);
}
__device__ __forceinline__ int ldi(const void* p, long long i, unsigned i64) {
    return i64 ? (int)((const long long*)p)[i] : ((const int*)p)[i];
}

__global__ __launch_bounds__(256) void k_zero(unsigned* __restrict__ p, int n) {
    int i = blockIdx.x * 256 + threadIdx.x;
    if (i < n) p[i] = 0;
}

// ---- format detector: flags[0]=x_f32, flags[1]=W_f32, flags[2]=ei_i64 ------
__global__ __launch_bounds__(256) void k_detect(const void* x, const void* W1,
                                                const void* ei, unsigned* flags) {
    __shared__ float smx[256];
    __shared__ float smw[256];
    __shared__ int   szc[256];
    int tid = threadIdx.x;
    const unsigned short* xu = (const unsigned short*)x;
    float mx = 0.f;
    for (int i = tid; i < 4096; i += 256) {
        unsigned short w = xu[i];
        if ((w & 0x7fffu) >= 0x7f80u) mx = 1e30f;
        else { float f = fabsf(bf2f(w)); if (f > mx) mx = f; }
    }
    smx[tid] = mx;
    const unsigned short* wu = (const unsigned short*)W1;
    float mw = 0.f;
    for (int i = tid; i < 4096; i += 256) {
        unsigned short w = wu[i];
        if ((w & 0x7fffu) >= 0x7f80u) mw = 1e30f;
        else { float f = fabsf(bf2f(w)); if (f > mw) mw = f; }
    }
    smw[tid] = mw;
    const int* eu = (const int*)ei;
    int zc = 0;
    for (int i = tid; i < 128; i += 256)
        if ((i & 1) && eu[i] == 0) ++zc;
    szc[tid] = zc;
    __syncthreads();
    for (int off = 128; off > 0; off >>= 1) {
        if (tid < off) {
            if (smx[tid + off] > smx[tid]) smx[tid] = smx[tid + off];
            if (smw[tid + off] > smw[tid]) smw[tid] = smw[tid + off];
            szc[tid] += szc[tid + off];
        }
        __syncthreads();
    }
    if (tid == 0) {
        flags[0] = (smx[0] > 1e4f) ? 1u : 0u;
        flags[1] = (smw[0] > 10.f) ? 1u : 0u;
        flags[2] = (szc[0] >= 56) ? 1u : 0u;
    }
}

// ---- degree count ----------------------------------------------------------
__global__ __launch_bounds__(256) void k_count(const void* ei, const unsigned* det,
                                               int* __restrict__ cnt, int E, int N) {
    int e = blockIdx.x * 256 + threadIdx.x;
    if (e >= E) return;
    int d = ldi(ei, (long long)E + e, det[2]);
    if ((unsigned)d < (unsigned)N) atomicAdd(&cnt[d], 1);
}

__global__ __launch_bounds__(256) void k_dinv(const int* __restrict__ cnt,
                                              float* __restrict__ dinv, int N) {
    int i = blockIdx.x * 256 + threadIdx.x;
    if (i < N) dinv[i] = rsqrtf((float)cnt[i] + 1.0f);  // +1 self-loop
}

// ---- exclusive scan (3-phase) ----------------------------------------------
__global__ __launch_bounds__(256) void k_scan_blk(const int* __restrict__ cnt,
                                                  int* __restrict__ pos,
                                                  int* __restrict__ bsum, int N) {
    __shared__ int sh[256];
    const int tid = threadIdx.x;
    const int base = blockIdx.x * 1024 + tid * 4;
    int v[4];
#pragma unroll
    for (int j = 0; j < 4; ++j) v[j] = (base + j < N) ? cnt[base + j] : 0;
    int s = v[0] + v[1] + v[2] + v[3];
    sh[tid] = s;
    __syncthreads();
    for (int off = 1; off < 256; off <<= 1) {
        int t = (tid >= off) ? sh[tid - off] : 0;
        __syncthreads();
        sh[tid] += t;
        __syncthreads();
    }
    int run = sh[tid] - s;
#pragma unroll
    for (int j = 0; j < 4; ++j) {
        if (base + j < N) pos[base + j] = run;
        run += v[j];
    }
    if (tid == 255) bsum[blockIdx.x] = sh[255];
}

__global__ void k_scan_top(int* __restrict__ bsum, int nb) {
    if (threadIdx.x == 0 && blockIdx.x == 0) {
        int running = 0;
        for (int b = 0; b < nb; ++b) {
            int t = bsum[b];
            bsum[b] = running;
            running += t;
        }
    }
}

__global__ __launch_bounds__(256) void k_scan_add(int* __restrict__ pos,
                                                  const int* __restrict__ bsum, int N) {
    int add = bsum[blockIdx.x];
    int base = blockIdx.x * 1024;
    for (int i = threadIdx.x; i < 1024; i += 256)
        if (base + i < N) pos[base + i] += add;
}

// ---- CSR fill --------------------------------------------------------------
__global__ __launch_bounds__(256) void k_fill(const void* ei, const unsigned* det,
                                              int* __restrict__ pos,
                                              int* __restrict__ srt, int E, int N) {
    int e = blockIdx.x * 256 + threadIdx.x;
    if (e >= E) return;
    unsigned i64 = det[2];
    int s = ldi(ei, e, i64);
    int d = ldi(ei, (long long)E + e, i64);
    if ((unsigned)d < (unsigned)N) {
        int slot = atomicAdd(&pos[d], 1);
        srt[slot] = ((unsigned)s < (unsigned)N) ? s : d;
    }
}

// ---- gemm1: h0'[N,128](bf16) = (x[N,256] @ W1[256,128]) * dinv[row] --------
// 32 rows x 128 cols per block; 4x4 thread tile.
__global__ __launch_bounds__(256) void k_gemm1(const void* x, const void* W1,
                                               const unsigned* det,
                                               const float* __restrict__ dinv,
                                               unsigned* __restrict__ Cp) {
    __shared__ float xs[32][33];
    __shared__ float wsh[32][128];
    const unsigned xf = det[0], wf = det[1];
    const int tid = threadIdx.x;
    const int r0 = blockIdx.x * 32;           // N % 32 == 0
    const int col = (tid & 31) * 4;
    const int row = (tid >> 5) * 4;
    float acc[4][4] = {};
    for (int k0 = 0; k0 < 256; k0 += 32) {
        for (int idx = tid; idx < 32 * 32; idx += 256) {
            int r = idx >> 5, kk = idx & 31;
            xs[r][kk] = ldf(x, (long long)(r0 + r) * 256 + k0 + kk, xf);
        }
        for (int idx = tid; idx < 32 * 128; idx += 256) {
            int kk = idx >> 7, c = idx & 127;
            wsh[kk][c] = ldf(W1, (long long)(k0 + kk) * 128 + c, wf);
        }
        __syncthreads();
#pragma unroll
        for (int kk = 0; kk < 32; ++kk) {
            float a0 = xs[row + 0][kk];
            float a1 = xs[row + 1][kk];
            float a2 = xs[row + 2][kk];
            float a3 = xs[row + 3][kk];
            const float4 b = *(const float4*)&wsh[kk][col];
            acc[0][0] += a0 * b.x; acc[0][1] += a0 * b.y; acc[0][2] += a0 * b.z; acc[0][3] += a0 * b.w;
            acc[1][0] += a1 * b.x; acc[1][1] += a1 * b.y; acc[1][2] += a1 * b.z; acc[1][3] += a1 * b.w;
            acc[2][0] += a2 * b.x; acc[2][1] += a2 * b.y; acc[2][2] += a2 * b.z; acc[2][3] += a2 * b.w;
            acc[3][0] += a3 * b.x; acc[3][1] += a3 * b.y; acc[3][2] += a3 * b.z; acc[3][3] += a3 * b.w;
        }
        __syncthreads();
    }
#pragma unroll
    for (int i = 0; i < 4; ++i) {
        float di = dinv[r0 + row + i];
        uint2 pv;
        pv.x = pack2(acc[i][0] * di, acc[i][1] * di);
        pv.y = pack2(acc[i][2] * di, acc[i][3] * di);
        *(uint2*)&Cp[(long long)(r0 + row + i) * 64 + (col >> 1)] = pv;
    }
}

// ---- gather over pre-scaled bf16[N,128] panel ------------------------------
// out[node] = op( dinv[node] * (sum_{s in nbrs} h'[s] + h'[node]) )
// one wave/node, 2 cols/lane (1 dword), 8-way predicated unroll.
__global__ __launch_bounds__(256) void k_gather(const unsigned* __restrict__ hp,
                                                const int* __restrict__ srt,
                                                const int* __restrict__ cnt,
                                                const int* __restrict__ pos,
                                                const float* __restrict__ dinv,
                                                const void* bias, const unsigned* det,
                                                int leaky, int prescaleOut,
                                                unsigned* __restrict__ outp, int N) {
    int node = blockIdx.x * 4 + (threadIdx.x >> 6);
    if (node >= N) return;
    int lane = threadIdx.x & 63;
    int end = pos[node];
    int beg = end - cnt[node];
    float dd = dinv[node];
    unsigned hv = hp[(long long)node * 64 + lane];
    float a0 = bf2f((unsigned short)(hv & 0xffffu));
    float a1 = bf2f((unsigned short)(hv >> 16));
    for (int q = beg; q < end; q += 8) {
        int s[8];
        unsigned v[8];
#pragma unroll
        for (int j = 0; j < 8; ++j) {
            int qq = q + j;
            s[j] = srt[(qq < end) ? qq : beg];   // loop entered => beg valid
        }
#pragma unroll
        for (int j = 0; j < 8; ++j)
            v[j] = hp[(long long)s[j] * 64 + lane];
#pragma unroll
        for (int j = 0; j < 8; ++j) {
            bool on = (q + j) < end;
            a0 += on ? bf2f((unsigned short)(v[j] & 0xffffu)) : 0.f;
            a1 += on ? bf2f((unsigned short)(v[j] >> 16)) : 0.f;
        }
    }
    a0 *= dd;
    a1 *= dd;
    if (bias) {
        a0 += ldf(bias, 2 * lane, det[1]);
        a1 += ldf(bias, 2 * lane + 1, det[1]);
    }
    if (leaky) {
        a0 = (a0 >= 0.f) ? a0 : 0.01f * a0;
        a1 = (a1 >= 0.f) ? a1 : 0.01f * a1;
    }
    if (prescaleOut) { a0 *= dd; a1 *= dd; }
    outp[(long long)node * 64 + lane] = pack2(a0, a1);
}

// ---- gemm2: [mu|lv](fp32) = ha[N,128](bf16) @ [Wmu;Wlv] + [bmu|blv] --------
// outMu aliases ha's memory (in-place): block reads only its own 32 rows
// (staged to LDS, complete before epilogue writes), blocks row-disjoint.
__global__ __launch_bounds__(256) void k_gemm2(const bf16_t* hap,
                                               const void* Wmu, const void* Wlv,
                                               const void* bmu, const void* blv,
                                               const unsigned* det,
                                               float* outMu, float* outLv) {
    __shared__ float as[32][33];
    __shared__ float wsh[32][128];
    const unsigned wf = det[1];
    const int tid = threadIdx.x;
    const int r0 = blockIdx.x * 32;
    const int col = (tid & 31) * 4;
    const int row = (tid >> 5) * 4;
    float acc[4][4] = {};
    for (int k0 = 0; k0 < 128; k0 += 32) {
        for (int idx = tid; idx < 32 * 32; idx += 256) {
            int r = idx >> 5, kk = idx & 31;
            as[r][kk] = bf2f(hap[(long long)(r0 + r) * 128 + k0 + kk]);
        }
        for (int idx = tid; idx < 32 * 128; idx += 256) {
            int kk = idx >> 7, c = idx & 127;
            wsh[kk][c] = (c < 64) ? ldf(Wmu, (long long)(k0 + kk) * 64 + c, wf)
                                  : ldf(Wlv, (long long)(k0 + kk) * 64 + (c - 64), wf);
        }
        __syncthreads();
#pragma unroll
        for (int kk = 0; kk < 32; ++kk) {
            float a0 = as[row + 0][kk];
            float a1 = as[row + 1][kk];
            float a2 = as[row + 2][kk];
            float a3 = as[row + 3][kk];
            const float4 b = *(const float4*)&wsh[kk][col];
            acc[0][0] += a0 * b.x; acc[0][1] += a0 * b.y; acc[0][2] += a0 * b.z; acc[0][3] += a0 * b.w;
            acc[1][0] += a1 * b.x; acc[1][1] += a1 * b.y; acc[1][2] += a1 * b.z; acc[1][3] += a1 * b.w;
            acc[2][0] += a2 * b.x; acc[2][1] += a2 * b.y; acc[2][2] += a2 * b.z; acc[2][3] += a2 * b.w;
            acc[3][0] += a3 * b.x; acc[3][1] += a3 * b.y; acc[3][2] += a3 * b.z; acc[3][3] += a3 * b.w;
        }
        __syncthreads();
    }
#pragma unroll
    for (int i = 0; i < 4; ++i)
#pragma unroll
        for (int j = 0; j < 4; ++j) {
            int c = col + j;
            float v = acc[i][j];
            if (c < 64) {
                v += ldf(bmu, c, wf);
                outMu[(long long)(r0 + row + i) * 64 + c] = v;
            } else {
                v += ldf(blv, c - 64, wf);
                outLv[(long long)(r0 + row + i) * 64 + (c - 64)] = v;
            }
        }
}

__global__ void k_sentinel(float* out, long long lvOff) {
    if (threadIdx.x == 0 && blockIdx.x == 0) {
        out[0] = 9.99e5f;
        out[lvOff] = 9.98e5f;
    }
}

extern "C" void kernel_launch(void* const* d_in, const int* in_sizes, int n_in,
                              void* d_out, int out_size, void* d_ws, size_t ws_size,
                              hipStream_t stream) {
    (void)out_size;
    const int N = 100000, E = 1600000;
    bool ok = (n_in == 8) && in_sizes[0] == 25600000 && in_sizes[1] == 3200000 &&
              in_sizes[2] == 32768 && in_sizes[3] == 128 &&
              in_sizes[4] == 8192 && in_sizes[5] == 64 &&
              in_sizes[6] == 8192 && in_sizes[7] == 64 &&
              ws_size >= (size_t)10 * 1024 * 1024;
    if (!ok) {
        k_sentinel<<<1, 64, 0, stream>>>((float*)d_out, (long long)N * 64);
        return;
    }
    const void* x   = d_in[0];
    const void* ei  = d_in[1];
    const void* W1  = d_in[2];
    const void* b1  = d_in[3];
    const void* Wmu = d_in[4];
    const void* bmu = d_in[5];
    const void* Wlv = d_in[6];
    const void* blv = d_in[7];

    char* w = (char*)d_ws;
    auto carve = [&](size_t bytes) {
        char* p = w;
        w += (bytes + 255) & ~(size_t)255;
        return p;
    };
    unsigned* flags = (unsigned*)carve(64);
    int*    cnt  = (int*)carve((size_t)N * 4);
    int*    pos  = (int*)carve((size_t)N * 4);
    float*  dinv = (float*)carve((size_t)N * 4);
    int*    bsum = (int*)carve(4096);
    int*    srt  = (int*)carve((size_t)E * 4);   // total ~7.7 MB

    float* M = (float*)d_out;                  // mu region / panel storage
    float* L = M + (size_t)N * 64;             // logvar region / panel storage
    unsigned* Mp = (unsigned*)M;               // bf16[N,128] as dword[N*64]
    unsigned* Lp = (unsigned*)L;

    const int nb = (N + 1023) / 1024;
    const int gblk = (N + 3) / 4;

    k_zero<<<1, 64, 0, stream>>>(flags, 16);
    k_detect<<<1, 256, 0, stream>>>(x, W1, ei, flags);
    k_zero<<<(N + 255) / 256, 256, 0, stream>>>((unsigned*)cnt, N);

    k_count<<<(E + 255) / 256, 256, 0, stream>>>(ei, flags, cnt, E, N);
    k_dinv<<<(N + 255) / 256, 256, 0, stream>>>(cnt, dinv, N);
    k_scan_blk<<<nb, 256, 0, stream>>>(cnt, pos, bsum, N);
    k_scan_top<<<1, 64, 0, stream>>>(bsum, nb);
    k_scan_add<<<nb, 256, 0, stream>>>(pos, bsum, N);
    k_fill<<<(E + 255) / 256, 256, 0, stream>>>(ei, flags, pos, srt, E, N);

    // h0' = (x@W1) * dinv[row]  -> bf16 panel in M
    k_gemm1<<<N / 32, 256, 0, stream>>>(x, W1, flags, dinv, Mp);
    // h'  = leaky(dd*(sum+self) + b1) * dd -> bf16 panel in L
    k_gather<<<gblk, 256, 0, stream>>>(Mp, srt, cnt, pos, dinv, b1, flags, 1, 1,
                                       Lp, N);
    // ha  = dd*(sum+self) -> bf16 panel in M (h0' dead)
    k_gather<<<gblk, 256, 0, stream>>>(Lp, srt, cnt, pos, dinv, nullptr, flags,
                                       0, 0, Mp, N);
    // [mu|lv] = ha @ [Wmu;Wlv] + bias -> fp32 M/L in-place
    k_gemm2<<<N / 32, 256, 0, stream>>>((const bf16_t*)Mp, Wmu, Wlv, bmu, blv,
                                        flags, M, L);
}